// Round 2
// baseline (476.320 us; speedup 1.0000x reference)
//
#include <hip/hip_runtime.h>

typedef _Float16 f16;
typedef _Float16 f16x4 __attribute__((ext_vector_type(4)));
typedef _Float16 f16x8 __attribute__((ext_vector_type(8)));
typedef float f32x4 __attribute__((ext_vector_type(4)));

#define MFMA_F16(a,b,c) __builtin_amdgcn_mfma_f32_16x16x32_f16((a),(b),(c),0,0,0)

// ---------------- LDS swizzles ----------------
// lds_x / ctx region: [64 rows][512 B] rows, XOR block bits 4-6 by (row&7)
__device__ __forceinline__ unsigned swx(int row, unsigned byte){
  return (unsigned)row*512u + (byte ^ ((((unsigned)row)&7u)<<4));
}
// per-wave arena: [96 rows][128 B] rows
__device__ __forceinline__ unsigned swa(unsigned base, int row, unsigned byte){
  return base + (unsigned)row*128u + (byte ^ ((((unsigned)row)&7u)<<4));
}

// ---------------- prep kernels ----------------
__global__ void prep_wt_k(const float* __restrict__ Wq, const float* __restrict__ Wk,
                          const float* __restrict__ Wv, const float* __restrict__ Wo,
                          f16* __restrict__ wt)
{
  int k = blockIdx.x & 255;
  int sel = blockIdx.x >> 8;
  const float* W = (sel==0)?Wq:(sel==1)?Wk:(sel==2)?Wv:Wo;
  f16* dst = wt + sel*65536;
  int n = threadIdx.x;
  dst[n*256 + k] = (f16)W[k*256 + n];   // WT[n][k] = W[k][n]
}

__device__ __forceinline__ float relcoord(int a){
  float v = (float)(a - 7) * (8.0f/7.0f);
  float t = log2f(fabsf(v) + 1.0f) * (1.0f/3.0f);   // /log2(8)
  return (v < 0.f) ? -t : t;
}

__global__ void prep_cpb_k(const float* __restrict__ w1, const float* __restrict__ b1,
                           const float* __restrict__ w2, float* __restrict__ bias_tbl)
{
  int row = blockIdx.x;            // 0..224
  int h = threadIdx.x;             // 0..511
  float t0 = relcoord(row/15);
  float t1 = relcoord(row%15);
  float hid = fmaxf(t0*w1[h] + t1*w1[512+h] + b1[h], 0.f);
  __shared__ float sm[8][8];
  int wv = h >> 6, ln = h & 63;
  #pragma unroll
  for (int n = 0; n < 8; ++n){
    float v = hid * w2[h*8 + n];
    #pragma unroll
    for (int off = 32; off > 0; off >>= 1) v += __shfl_down(v, off, 64);
    if (ln == 0) sm[wv][n] = v;
  }
  __syncthreads();
  if (h < 8){
    float s = 0.f;
    #pragma unroll
    for (int u = 0; u < 8; ++u) s += sm[u][h];
    bias_tbl[row*8 + h] = s;
  }
}

__global__ void prep_bias_k(const float* __restrict__ bias_tbl, float* __restrict__ bias16)
{
  int idx = blockIdx.x*256 + threadIdx.x;   // h*4096 + n*64 + m, 32768 total
  int h = idx >> 12;
  int n = (idx >> 6) & 63;
  int m = idx & 63;
  int rel = ((n>>3) - (m>>3) + 7)*15 + ((n&7) - (m&7) + 7);
  float b = bias_tbl[rel*8 + h];
  bias16[idx] = 16.f / (1.f + __expf(-b));
}

// ---------------- main kernel ----------------
// A-frag: A[row=l&15][k=(l>>4)*8+e]; B-frag: B[k=(l>>4)*8+e][col=l&15]
// D: col=l&15, row=(l>>4)*4+reg   (guide §3, m89-verified)
__device__ __forceinline__ void gemm_x(const char* smem, const f16* __restrict__ WT,
                                       int cb, int l15, int lhi, f32x4 acc[4][2])
{
  #pragma unroll
  for (int mt=0; mt<4; ++mt){
    acc[mt][0] = f32x4{0.f,0.f,0.f,0.f};
    acc[mt][1] = f32x4{0.f,0.f,0.f,0.f};
  }
  #pragma unroll
  for (int ks=0; ks<8; ++ks){
    f16x8 B0 = *(const f16x8*)(WT + (size_t)(cb + l15)*256      + ks*32 + lhi*8);
    f16x8 B1 = *(const f16x8*)(WT + (size_t)(cb + 16 + l15)*256 + ks*32 + lhi*8);
    #pragma unroll
    for (int mt=0; mt<4; ++mt){
      f16x8 A = *(const f16x8*)(smem + swx(mt*16 + l15, (unsigned)(ks*64 + lhi*16)));
      acc[mt][0] = MFMA_F16(A, B0, acc[mt][0]);
      acc[mt][1] = MFMA_F16(A, B1, acc[mt][1]);
    }
  }
}

__global__ __launch_bounds__(512, 2)
void swin_main_k(const float* __restrict__ x,
                 const float* __restrict__ bq, const float* __restrict__ bv,
                 const float* __restrict__ bo, const float* __restrict__ ls,
                 const f16* __restrict__ wt, const float* __restrict__ bias16,
                 float* __restrict__ out)
{
  extern __shared__ char smem[];
  const int tid = threadIdx.x;
  const int lane = tid & 63;
  const int w = tid >> 6;                 // wave id == head id
  const int l15 = lane & 15, lhi = lane >> 4;
  const int cb = w*32;                    // channel base of this head
  const unsigned arena = 32768u + (unsigned)w*12288u;

  const int bw = blockIdx.x;
  const int bI = bw >> 8, wh = (bw >> 4) & 15, ww = bw & 15;
  const size_t img = (size_t)bI * (128*128*256);
  const f16* WqT = wt;
  const f16* WkT = wt + 65536;
  const f16* WvT = wt + 131072;
  const f16* WoT = wt + 196608;

  // ---- stage x window -> lds_x f16 [64][256] (swizzled) ----
  #pragma unroll
  for (int i = 0; i < 8; ++i){
    int r = w*8 + i;
    const float* src = x + img + ((size_t)((wh*8 + (r>>3))*128 + ww*8 + (r&7)))*256 + lane*4;
    float4 v = *(const float4*)src;
    f16x4 hv = { (f16)v.x, (f16)v.y, (f16)v.z, (f16)v.w };
    *(f16x4*)(smem + swx(r, (unsigned)(lane*8))) = hv;
  }
  __syncthreads();

  f32x4 acc[4][2];

  // ---- Q projection + cosine-normalize -> qn (arena rows 0..63, bytes 0..63) ----
  gemm_x(smem, WqT, cb, l15, lhi, acc);
  {
    float b0 = bq[cb + l15], b1 = bq[cb + 16 + l15];
    #pragma unroll
    for (int mt=0; mt<4; ++mt){
      #pragma unroll
      for (int e=0; e<4; ++e){
        float v0 = acc[mt][0][e] + b0;
        float v1 = acc[mt][1][e] + b1;
        float s = v0*v0 + v1*v1;
        s += __shfl_xor(s, 1); s += __shfl_xor(s, 2);
        s += __shfl_xor(s, 4); s += __shfl_xor(s, 8);
        float inv = 1.0f / fmaxf(sqrtf(s), 1e-12f);
        int row = mt*16 + lhi*4 + e;
        *(f16*)(smem + swa(arena, row, (unsigned)(l15*2)))      = (f16)(v0*inv);
        *(f16*)(smem + swa(arena, row, (unsigned)((16+l15)*2))) = (f16)(v1*inv);
      }
    }
  }

  // ---- K projection + normalize -> kn (arena rows 0..63, bytes 64..127) ----
  gemm_x(smem, WkT, cb, l15, lhi, acc);
  {
    #pragma unroll
    for (int mt=0; mt<4; ++mt){
      #pragma unroll
      for (int e=0; e<4; ++e){
        float v0 = acc[mt][0][e];
        float v1 = acc[mt][1][e];
        float s = v0*v0 + v1*v1;
        s += __shfl_xor(s, 1); s += __shfl_xor(s, 2);
        s += __shfl_xor(s, 4); s += __shfl_xor(s, 8);
        float inv = 1.0f / fmaxf(sqrtf(s), 1e-12f);
        int row = mt*16 + lhi*4 + e;
        *(f16*)(smem + swa(arena, row, (unsigned)(64 + l15*2)))      = (f16)(v0*inv);
        *(f16*)(smem + swa(arena, row, (unsigned)(64 + (16+l15)*2))) = (f16)(v1*inv);
      }
    }
  }

  // ---- V projection (keep in regs) ----
  f32x4 vac[4][2];
  gemm_x(smem, WvT, cb, l15, lhi, vac);
  {
    float b0 = bv[cb + l15], b1 = bv[cb + 16 + l15];
    #pragma unroll
    for (int mt=0; mt<4; ++mt){
      #pragma unroll
      for (int e=0; e<4; ++e){ vac[mt][0][e] += b0; vac[mt][1][e] += b1; }
    }
  }

  // write vT[d][token] (arena rows 64..95)
  #pragma unroll
  for (int mt=0; mt<4; ++mt){
    #pragma unroll
    for (int e=0; e<4; ++e){
      int token = mt*16 + lhi*4 + e;
      *(f16*)(smem + swa(arena, 64 + l15,      (unsigned)(token*2))) = (f16)vac[mt][0][e];
      *(f16*)(smem + swa(arena, 64 + 16 + l15, (unsigned)(token*2))) = (f16)vac[mt][1][e];
    }
  }
  __syncthreads();   // all waves done reading lds_x (ctx will overwrite it)

  // ---- scores S = qn·kn^T (K=32, one MFMA step) ----
  f16x8 Aq[4], Bk[4];
  #pragma unroll
  for (int mt=0; mt<4; ++mt)
    Aq[mt] = *(const f16x8*)(smem + swa(arena, mt*16 + l15, (unsigned)(lhi*16)));
  #pragma unroll
  for (int nt=0; nt<4; ++nt)
    Bk[nt] = *(const f16x8*)(smem + swa(arena, nt*16 + l15, (unsigned)(64 + lhi*16)));
  f32x4 sc[4][4];
  #pragma unroll
  for (int mt=0; mt<4; ++mt){
    #pragma unroll
    for (int nt=0; nt<4; ++nt){
      f32x4 z = f32x4{0.f,0.f,0.f,0.f};
      sc[mt][nt] = MFMA_F16(Aq[mt], Bk[nt], z);
    }
  }

  // ---- softmax (fp32, wave-parallel) + write P f16 (arena rows 0..63) ----
  float scale = __expf(fminf(ls[w], 4.605170185988091f));   // ln(100)
  const float* bb = bias16 + (size_t)w*4096;
  #pragma unroll
  for (int mt=0; mt<4; ++mt){
    #pragma unroll
    for (int e=0; e<4; ++e){
      int n = mt*16 + lhi*4 + e;
      float s0 = sc[mt][0][e]*scale + bb[n*64 + l15];
      float s1 = sc[mt][1][e]*scale + bb[n*64 + 16 + l15];
      float s2 = sc[mt][2][e]*scale + bb[n*64 + 32 + l15];
      float s3 = sc[mt][3][e]*scale + bb[n*64 + 48 + l15];
      float mx = fmaxf(fmaxf(s0,s1), fmaxf(s2,s3));
      mx = fmaxf(mx, __shfl_xor(mx,1)); mx = fmaxf(mx, __shfl_xor(mx,2));
      mx = fmaxf(mx, __shfl_xor(mx,4)); mx = fmaxf(mx, __shfl_xor(mx,8));
      s0 = __expf(s0-mx); s1 = __expf(s1-mx);
      s2 = __expf(s2-mx); s3 = __expf(s3-mx);
      float sm = s0+s1+s2+s3;
      sm += __shfl_xor(sm,1); sm += __shfl_xor(sm,2);
      sm += __shfl_xor(sm,4); sm += __shfl_xor(sm,8);
      float r = 1.0f / sm;
      *(f16*)(smem + swa(arena, n, (unsigned)(l15*2)))      = (f16)(s0*r);
      *(f16*)(smem + swa(arena, n, (unsigned)((16+l15)*2))) = (f16)(s1*r);
      *(f16*)(smem + swa(arena, n, (unsigned)((32+l15)*2))) = (f16)(s2*r);
      *(f16*)(smem + swa(arena, n, (unsigned)((48+l15)*2))) = (f16)(s3*r);
    }
  }

  // ---- ctx = P @ V  (K=64, two MFMA steps) ----
  f32x4 cac[4][2];
  #pragma unroll
  for (int mt=0; mt<4; ++mt){
    cac[mt][0] = f32x4{0.f,0.f,0.f,0.f};
    cac[mt][1] = f32x4{0.f,0.f,0.f,0.f};
  }
  #pragma unroll
  for (int ks=0; ks<2; ++ks){
    f16x8 Bv0 = *(const f16x8*)(smem + swa(arena, 64 + l15,      (unsigned)(ks*64 + lhi*16)));
    f16x8 Bv1 = *(const f16x8*)(smem + swa(arena, 64 + 16 + l15, (unsigned)(ks*64 + lhi*16)));
    #pragma unroll
    for (int mt=0; mt<4; ++mt){
      f16x8 Ap = *(const f16x8*)(smem + swa(arena, mt*16 + l15, (unsigned)(ks*64 + lhi*16)));
      cac[mt][0] = MFMA_F16(Ap, Bv0, cac[mt][0]);
      cac[mt][1] = MFMA_F16(Ap, Bv1, cac[mt][1]);
    }
  }

  // ---- ctx -> lds_x region (f16, all heads concatenated) ----
  #pragma unroll
  for (int mt=0; mt<4; ++mt){
    #pragma unroll
    for (int e=0; e<4; ++e){
      int token = mt*16 + lhi*4 + e;
      *(f16*)(smem + swx(token, (unsigned)((cb + l15)*2)))      = (f16)cac[mt][0][e];
      *(f16*)(smem + swx(token, (unsigned)((cb + 16 + l15)*2))) = (f16)cac[mt][1][e];
    }
  }
  __syncthreads();

  // ---- out = ctx @ Wo + bo, window-reverse store ----
  gemm_x(smem, WoT, cb, l15, lhi, acc);
  {
    float b0 = bo[cb + l15], b1 = bo[cb + 16 + l15];
    #pragma unroll
    for (int mt=0; mt<4; ++mt){
      #pragma unroll
      for (int e=0; e<4; ++e){
        int token = mt*16 + lhi*4 + e;
        size_t o = img + ((size_t)((wh*8 + (token>>3))*128 + ww*8 + (token&7)))*256;
        out[o + cb + l15]      = acc[mt][0][e] + b0;
        out[o + cb + 16 + l15] = acc[mt][1][e] + b1;
      }
    }
  }
}

// ---------------- launch ----------------
extern "C" void kernel_launch(void* const* d_in, const int* in_sizes, int n_in,
                              void* d_out, int out_size, void* d_ws, size_t ws_size,
                              hipStream_t stream)
{
  const float* x   = (const float*)d_in[0];
  const float* Wq  = (const float*)d_in[1];
  const float* bq  = (const float*)d_in[2];
  const float* Wk  = (const float*)d_in[3];
  const float* Wv  = (const float*)d_in[4];
  const float* bv  = (const float*)d_in[5];
  const float* Wo  = (const float*)d_in[6];
  const float* bo  = (const float*)d_in[7];
  const float* w1  = (const float*)d_in[8];
  const float* b1  = (const float*)d_in[9];
  const float* w2  = (const float*)d_in[10];
  const float* lsc = (const float*)d_in[11];
  float* out = (float*)d_out;

  f16*   wt       = (f16*)d_ws;                                   // 4 x 64K f16 = 512 KB
  float* bias_tbl = (float*)((char*)d_ws + 524288);               // 225*8 fp32
  float* bias16   = (float*)((char*)d_ws + 524288 + 7680);        // 8*64*64 fp32

  hipLaunchKernelGGL(prep_wt_k,  dim3(1024), dim3(256), 0, stream, Wq, Wk, Wv, Wo, wt);
  hipLaunchKernelGGL(prep_cpb_k, dim3(225),  dim3(512), 0, stream, w1, b1, w2, bias_tbl);
  hipLaunchKernelGGL(prep_bias_k,dim3(128),  dim3(256), 0, stream, bias_tbl, bias16);

  (void)hipFuncSetAttribute((const void*)swin_main_k,
                            hipFuncAttributeMaxDynamicSharedMemorySize, 131072);
  hipLaunchKernelGGL(swin_main_k, dim3(2048), dim3(512), 131072, stream,
                     x, bq, bv, bo, lsc, wt, bias16, out);
}